// Round 11
// baseline (117.856 us; speedup 1.0000x reference)
//
#include <hip/hip_runtime.h>
#include <stdint.h>

#define K_DIM 4096
#define KW 1024          // packed words per m-row
#define M_DIM 11008
#define B_DIM 16
#define GROUP_ROWS 2752  // M / 4 groups

typedef int v4i __attribute__((ext_vector_type(4)));

// spread low byte p (4x 2-bit fields) into 4 bytes: {p&3,(p>>2)&3,(p>>4)&3,(p>>6)&3}
__device__ __forceinline__ int spread2(int p) {
    int t = p | (p << 12);
    return (t & 0x00030003) | (((t >> 2) & 0x00030003) << 8);
}
__device__ __forceinline__ int dot4(int a, int b, int c) {
    return __builtin_amdgcn_sdot4(a, b, c, false);
}

// ---------------- kernel 1: per-row activation quantization (R8 verbatim) ----------------
__global__ __launch_bounds__(1024) void quant_k(const float* __restrict__ in,
                                                int* __restrict__ qg,
                                                int* __restrict__ sumq,
                                                float* __restrict__ invs) {
    const int b = blockIdx.x, t = threadIdx.x;
    const int lane = t & 63, wid = t >> 6;  // 16 waves

    float4 v = ((const float4*)(in + (size_t)b * K_DIM))[t];
    float mx = fmaxf(fmaxf(fabsf(v.x), fabsf(v.y)), fmaxf(fabsf(v.z), fabsf(v.w)));
#pragma unroll
    for (int s = 1; s < 64; s <<= 1) mx = fmaxf(mx, __shfl_xor(mx, s, 64));

    __shared__ float wmax[16];
    __shared__ int wsum[16];
    if (lane == 0) wmax[wid] = mx;
    __syncthreads();
    float bm = wmax[0];
#pragma unroll
    for (int i = 1; i < 16; ++i) bm = fmaxf(bm, wmax[i]);
    const float sc = 127.f / fmaxf(bm, 1e-5f);

    float xs[4] = {v.x, v.y, v.z, v.w};
    int w = 0, ss = 0;
#pragma unroll
    for (int j = 0; j < 4; ++j) {
        int q = (int)rintf(xs[j] * sc);   // round-half-even, matches jnp.round
        q = q > 127 ? 127 : (q < -128 ? -128 : q);
        ss += q;
        w |= (q & 255) << (8 * j);
    }
    qg[b * KW + t] = w;

#pragma unroll
    for (int s = 1; s < 64; s <<= 1) ss += __shfl_xor(ss, s, 64);
    if (lane == 0) wsum[wid] = ss;
    __syncthreads();
    if (t == 0) {
        int tot = 0;
#pragma unroll
        for (int i = 0; i < 16; ++i) tot += wsum[i];
        sumq[b] = tot;
        invs[b] = fmaxf(bm, 1e-5f) / 127.f;
    }
}

// ---------------- kernel 2: ternary GEMM (R8 verbatim — best known, 19.9 us) ----------------
__global__ __launch_bounds__(256, 2) void gemm_k(const int* __restrict__ wp,
                                                 const int* __restrict__ qg,
                                                 const int* __restrict__ sumq,
                                                 const float* __restrict__ invs,
                                                 const float* __restrict__ wscale,
                                                 float* __restrict__ out) {
    __shared__ v4i wbuf[4 * 1024];  // 64 KB: wave wid -> [wid*1024, wid*1024+1024)
    __shared__ int red[4 * 64 * 4]; // 4 KB
    const int t = threadIdx.x, lane = t & 63, wid = t >> 6;
    const int m0 = blockIdx.x * 16;
    const int lrow = lane & 15;
    const int lgrp = lane >> 4;

    v4i qr[16];
#pragma unroll
    for (int s = 0; s < 16; ++s)
        qr[s] = *(const v4i*)(qg + lrow * KW + wid * 256 + s * 16 + lgrp * 4);

    v4i wst[16];
#pragma unroll
    for (int c = 0; c < 4; ++c)
#pragma unroll
        for (int i = 0; i < 4; ++i) {
            const int row = i * 4 + lgrp;
            wst[c * 4 + i] = __builtin_nontemporal_load(
                (const v4i*)(wp + (size_t)(m0 + row) * KW + wid * 256 + c * 64 + lrow * 4));
        }

    v4i acc = {0, 0, 0, 0};
#pragma unroll
    for (int c = 0; c < 4; ++c) {
#pragma unroll
        for (int i = 0; i < 4; ++i) {
            const int row = i * 4 + lgrp;
            wbuf[wid * 1024 + c * 256 + row * 16 + (lrow ^ (row & 7))] = wst[c * 4 + i];
        }
        asm volatile("s_waitcnt lgkmcnt(0)" ::: "memory");
#pragma unroll
        for (int sp = 0; sp < 4; ++sp) {
            v4i wv = wbuf[wid * 1024 + c * 256 + lrow * 16 + ((sp * 4 + lgrp) ^ (lrow & 7))];
            v4i bb;
            bb[0] = spread2(wv[0]); bb[1] = spread2(wv[1]);
            bb[2] = spread2(wv[2]); bb[3] = spread2(wv[3]);
            acc = __builtin_amdgcn_mfma_i32_16x16x64_i8(qr[c * 4 + sp], bb, acc, 0, 0, 0);
        }
    }

    *(v4i*)(red + (wid * 64 + lane) * 4) = acc;
    __syncthreads();

    const int b = t >> 4, m = t & 15;
    const int src_lane = ((b >> 2) << 4) | m;
    const int reg = b & 3;
    int sum = red[(0 * 64 + src_lane) * 4 + reg] + red[(1 * 64 + src_lane) * 4 + reg] +
              red[(2 * 64 + src_lane) * 4 + reg] + red[(3 * 64 + src_lane) * 4 + reg];
    const float val = (float)(sum - sumq[b]) * invs[b] * wscale[m0 / GROUP_ROWS];
    out[(size_t)b * M_DIM + m0 + m] = val;
}

// ---------------- DIAGNOSTIC: pure streaming read of the weight array ----------------
// 8 full passes over 45.1 MB (361 MB touched) -> big enough to surface in top-5
// with real counters. Consumption = 1 sdot4 per int4 (negligible). Effective BW
// = 361 MB / dur. FETCH_SIZE tells whether L3 served the re-reads.
__global__ __launch_bounds__(256) void diag_read_k(const int* __restrict__ wp,
                                                   int* __restrict__ sink) {
    const size_t total4 = (size_t)M_DIM * KW / 4;  // 2,818,048 int4s
    const size_t stride = (size_t)gridDim.x * 256;
    const size_t tid = (size_t)blockIdx.x * 256 + threadIdx.x;
    int acc = 0;
    for (int pass = 0; pass < 8; ++pass) {
        for (size_t i = tid; i < total4; i += stride) {
            v4i v = *(const v4i*)(wp + i * 4);
            acc = dot4(v[0] ^ v[1], v[2] ^ v[3], acc);
        }
    }
    sink[tid] = acc;  // prevent DCE
}

extern "C" void kernel_launch(void* const* d_in, const int* in_sizes, int n_in,
                              void* d_out, int out_size, void* d_ws, size_t ws_size,
                              hipStream_t stream) {
    const float* inp    = (const float*)d_in[0];
    const int*   wp     = (const int*)d_in[1];
    const float* wscale = (const float*)d_in[2];
    float* out = (float*)d_out;

    int*   qg   = (int*)d_ws;               // 16384 words = 64 KB
    int*   sumq = qg + B_DIM * KW;          // 16 ints
    float* invs = (float*)(sumq + B_DIM);   // 16 floats
    int*   sinkA = qg + 32768;              // 2048*256 ints = 2 MB
    int*   sinkB = sinkA + 2048 * 256;      // 688*256 ints

    quant_k<<<dim3(B_DIM), dim3(1024), 0, stream>>>(inp, qg, sumq, invs);
    gemm_k<<<dim3(M_DIM / 16), dim3(256), 0, stream>>>(wp, qg, sumq, invs, wscale, out);
    // diag A: copy-bench occupancy (2048 blocks ~ 32 waves/CU)
    diag_read_k<<<dim3(2048), dim3(256), 0, stream>>>(wp, sinkA);
    // diag B: gemm-like occupancy (688 blocks ~ 11 waves/CU)
    diag_read_k<<<dim3(688), dim3(256), 0, stream>>>(wp, sinkB);
}

// Round 13
// 22.516 us; speedup vs baseline: 5.2343x; 5.2343x over previous
//
#include <hip/hip_runtime.h>
#include <stdint.h>

#define K_DIM 4096
#define KW 1024          // packed words per m-row
#define M_DIM 11008
#define B_DIM 16
#define GROUP_ROWS 2752  // M / 4 groups
#define QTR_W 256

typedef int v4i __attribute__((ext_vector_type(4)));

// spread low byte p (4x 2-bit fields) into 4 bytes: {p&3,(p>>2)&3,(p>>4)&3,(p>>6)&3}
__device__ __forceinline__ int spread2(int p) {
    int t = p | (p << 12);
    return (t & 0x00030003) | (((t >> 2) & 0x00030003) << 8);
}

// ---------------- kernel 1: per-row activation quantization ----------------
// 64 blocks x 256 thr: block g -> row b=g>>2, quarter qt=g&3. Full-row absmax
// (redundant, L2-hot), quantize own quarter. Partial sums to sumq_part[b][qt].
__global__ __launch_bounds__(256) void quant_k(const float* __restrict__ in,
                                               int* __restrict__ qg,
                                               int* __restrict__ sumq_part,
                                               float* __restrict__ invs) {
    const int g = blockIdx.x, b = g >> 2, qt = g & 3;
    const int t = threadIdx.x, lane = t & 63, wid = t >> 6;

    const float4* row = (const float4*)(in + (size_t)b * K_DIM);
    float4 v[4];
#pragma unroll
    for (int i = 0; i < 4; ++i) v[i] = row[t + i * 256];

    float mx = 0.f;
#pragma unroll
    for (int i = 0; i < 4; ++i) {
        mx = fmaxf(mx, fabsf(v[i].x)); mx = fmaxf(mx, fabsf(v[i].y));
        mx = fmaxf(mx, fabsf(v[i].z)); mx = fmaxf(mx, fabsf(v[i].w));
    }
#pragma unroll
    for (int s = 1; s < 64; s <<= 1) mx = fmaxf(mx, __shfl_xor(mx, s, 64));

    __shared__ float wmax[4];
    __shared__ int wsum[4];
    if (lane == 0) wmax[wid] = mx;
    __syncthreads();
    const float bm = fmaxf(fmaxf(wmax[0], wmax[1]), fmaxf(wmax[2], wmax[3]));
    const float sc = 127.f / fmaxf(bm, 1e-5f);

    const float4 mine = v[qt];  // thread t quantizes word qt*256 + t
    float xs[4] = {mine.x, mine.y, mine.z, mine.w};
    int w = 0, ss = 0;
#pragma unroll
    for (int j = 0; j < 4; ++j) {
        int q = (int)rintf(xs[j] * sc);   // round-half-even, matches jnp.round
        q = q > 127 ? 127 : (q < -128 ? -128 : q);
        ss += q;
        w |= (q & 255) << (8 * j);
    }
    qg[b * KW + qt * QTR_W + t] = w;

#pragma unroll
    for (int s = 1; s < 64; s <<= 1) ss += __shfl_xor(ss, s, 64);
    if (lane == 0) wsum[wid] = ss;
    __syncthreads();
    if (t == 0) {
        sumq_part[b * 4 + qt] = wsum[0] + wsum[1] + wsum[2] + wsum[3];
        if (qt == 0) invs[b] = fmaxf(bm, 1e-5f) / 127.f;
    }
}

// ---------------- kernel 2: pipelined ternary GEMM via mfma_i32_16x16x64_i8 ----------------
// 688 blocks x 256 thr (4 decoupled waves). Wave wid owns k-words [wid*256,(wid+1)*256)
// of 16 m-rows (16 KB), consumed in 4 chunks of 4 KB through a per-wave ping-pong
// pair of LDS slots. Iteration c: {ds_read chunk c} -> {ds_write chunk c+1} ->
// {MFMA c} -> {global loads chunk c+2}. The refill of wst[p]/qd[p] is AFTER the
// MFMA that consumes them (fixes R12's data hazard: p=(c+2)&1 == c&1, so an
// early refill clobbered chunk c's q). Scheduler may still hoist refill loads
// via register renaming. LDS = 32 KB (reduce aliased) -> 4 blocks/CU, 16 waves/CU.
__global__ __launch_bounds__(256, 4) void gemm_k(const int* __restrict__ wp,
                                                 const int* __restrict__ qg,
                                                 const int* __restrict__ sumq_part,
                                                 const float* __restrict__ invs,
                                                 const float* __restrict__ wscale,
                                                 float* __restrict__ out) {
    __shared__ v4i wbuf[4][2][256];  // 32 KB: [wave][slot][row*16 + col]
    const int t = threadIdx.x, lane = t & 63, wid = t >> 6;
    const int m0 = blockIdx.x * 16;
    const int lrow = lane & 15;   // b for A-frag, m-offset for B-frag
    const int lgrp = lane >> 4;   // k-group within the 64-k MFMA step

    // global address helpers (chunk c = 64 words/row)
    const int* wbase = wp + (size_t)m0 * KW + wid * QTR_W + lrow * 4;
    const int* qbase = qg + lrow * KW + wid * QTR_W + lgrp * 4;

#define WLOAD(c, i) __builtin_nontemporal_load( \
        (const v4i*)(wbase + (size_t)((i) * 4 + lgrp) * KW + (c) * 64))
#define QLOAD(c, sp) (*(const v4i*)(qbase + (c) * 64 + (sp) * 16))
#define WSTORE(slot, i, val) { const int row_ = (i) * 4 + lgrp; \
        wbuf[wid][slot][row_ * 16 + (lrow ^ (row_ & 7))] = (val); }

    v4i qd[2][4], wst[2][4];
    // prologue: q chunk0 (oldest), w chunk0, w chunk1, q chunk1
#pragma unroll
    for (int sp = 0; sp < 4; ++sp) qd[0][sp] = QLOAD(0, sp);
#pragma unroll
    for (int i = 0; i < 4; ++i) wst[0][i] = WLOAD(0, i);
#pragma unroll
    for (int i = 0; i < 4; ++i) wst[1][i] = WLOAD(1, i);
#pragma unroll
    for (int sp = 0; sp < 4; ++sp) qd[1][sp] = QLOAD(1, sp);
    // write chunk0 -> slot0 (compiler emits counted vmcnt for wst[0])
#pragma unroll
    for (int i = 0; i < 4; ++i) WSTORE(0, i, wst[0][i]);

    v4i acc = {0, 0, 0, 0};
#pragma unroll
    for (int c = 0; c < 4; ++c) {
        const int p = c & 1, n = p ^ 1;
        // 1) LDS reads of chunk c
        v4i wv[4];
#pragma unroll
        for (int sp = 0; sp < 4; ++sp)
            wv[sp] = wbuf[wid][p][lrow * 16 + ((sp * 4 + lgrp) ^ (lrow & 7))];
        // 2) stage chunk c+1 into the other slot (data = wst[n], loaded earlier)
        if (c < 3) {
#pragma unroll
            for (int i = 0; i < 4; ++i) WSTORE(n, i, wst[n][i]);
        }
        // 3) MFMA on chunk c — qd[p] still holds chunk c's q (hazard-free order)
#pragma unroll
        for (int sp = 0; sp < 4; ++sp) {
            v4i bb;
            bb[0] = spread2(wv[sp][0]); bb[1] = spread2(wv[sp][1]);
            bb[2] = spread2(wv[sp][2]); bb[3] = spread2(wv[sp][3]);
            acc = __builtin_amdgcn_mfma_i32_16x16x64_i8(qd[p][sp], bb, acc, 0, 0, 0);
        }
        // 4) refill regs with chunk c+2 (after last use of wst[p]/qd[p])
        if (c < 2) {
#pragma unroll
            for (int i = 0; i < 4; ++i) wst[p][i] = WLOAD(c + 2, i);
#pragma unroll
            for (int sp = 0; sp < 4; ++sp) qd[p][sp] = QLOAD(c + 2, sp);
        }
    }
#undef WLOAD
#undef QLOAD
#undef WSTORE

    // ---- cross-wave reduce (reuse wbuf; only barriers in the kernel) ----
    __syncthreads();
    int* red = (int*)&wbuf[0][0][0];
    *(v4i*)(red + (wid * 64 + lane) * 4) = acc;
    __syncthreads();

    // thread t -> output (b = t>>4, m = t&15); D layout: col=lane&15, row=(lane>>4)*4+reg
    const int b = t >> 4, m = t & 15;
    const int src_lane = ((b >> 2) << 4) | m;
    const int reg = b & 3;
    int sum = red[(0 * 64 + src_lane) * 4 + reg] + red[(1 * 64 + src_lane) * 4 + reg] +
              red[(2 * 64 + src_lane) * 4 + reg] + red[(3 * 64 + src_lane) * 4 + reg];
    const int sq = sumq_part[b * 4 + 0] + sumq_part[b * 4 + 1] +
                   sumq_part[b * 4 + 2] + sumq_part[b * 4 + 3];
    const float val = (float)(sum - sq) * invs[b] * wscale[m0 / GROUP_ROWS];
    out[(size_t)b * M_DIM + m0 + m] = val;
}

extern "C" void kernel_launch(void* const* d_in, const int* in_sizes, int n_in,
                              void* d_out, int out_size, void* d_ws, size_t ws_size,
                              hipStream_t stream) {
    const float* inp    = (const float*)d_in[0];
    const int*   wp     = (const int*)d_in[1];
    const float* wscale = (const float*)d_in[2];
    float* out = (float*)d_out;

    int*   qg   = (int*)d_ws;                  // 16384 words = 64 KB
    int*   sqp  = qg + B_DIM * KW;             // 64 ints
    float* invs = (float*)(sqp + B_DIM * 4);   // 16 floats

    quant_k<<<dim3(B_DIM * 4), dim3(256), 0, stream>>>(inp, qg, sqp, invs);
    gemm_k<<<dim3(M_DIM / 16), dim3(256), 0, stream>>>(wp, qg, sqp, invs, wscale, out);
}